// Round 16
// baseline (165.310 us; speedup 1.0000x reference)
//
#include <hip/hip_runtime.h>
#include <hip/hip_bf16.h>

#define B_ 4
#define N_ 1024
#define C_ 1024
#define H_ 16
#define D_ 64

typedef __attribute__((ext_vector_type(8))) short bf16x8;
typedef __attribute__((ext_vector_type(4))) float f32x4;
typedef __attribute__((ext_vector_type(4))) int i32x4;

__device__ __forceinline__ void gld_lds16(const void* g, void* l) {
    __builtin_amdgcn_global_load_lds(
        (const __attribute__((address_space(1))) void*)g,
        (__attribute__((address_space(3))) void*)l, 16, 0, 0);
}

__device__ __forceinline__ unsigned cvt_pk_bf16(float lo, float hi) {
    unsigned r;
    asm("v_cvt_pk_bf16_f32 %0, %1, %2" : "=v"(r) : "v"(lo), "v"(hi));
    return r;
}

// ---------------------------------------------------------------- fp32 -> bf16
__global__ __launch_bounds__(256) void f2b_kernel(const float* __restrict__ s,
                                                  __hip_bfloat16* __restrict__ d,
                                                  int n) {
    int i = (blockIdx.x * 256 + threadIdx.x) * 4;
    if (i < n) {
        float4 v = *(const float4*)&s[i];
        d[i + 0] = __float2bfloat16(v.x);
        d[i + 1] = __float2bfloat16(v.y);
        d[i + 2] = __float2bfloat16(v.z);
        d[i + 3] = __float2bfloat16(v.w);
    }
}

// 4 weight matrices in one dispatch (blockIdx.y selects)
__global__ __launch_bounds__(256) void f2b4_kernel(const float* __restrict__ w0,
                                                   const float* __restrict__ w1,
                                                   const float* __restrict__ w2,
                                                   const float* __restrict__ w3,
                                                   __hip_bfloat16* __restrict__ d0,
                                                   __hip_bfloat16* __restrict__ d1,
                                                   __hip_bfloat16* __restrict__ d2,
                                                   __hip_bfloat16* __restrict__ d3) {
    int sel = blockIdx.y;
    const float* s = sel == 0 ? w0 : sel == 1 ? w1 : sel == 2 ? w2 : w3;
    __hip_bfloat16* d = sel == 0 ? d0 : sel == 1 ? d1 : sel == 2 ? d2 : d3;
    int i = (blockIdx.x * 256 + threadIdx.x) * 4;
    float4 v = *(const float4*)&s[i];
    d[i + 0] = __float2bfloat16(v.x);
    d[i + 1] = __float2bfloat16(v.y);
    d[i + 2] = __float2bfloat16(v.z);
    d[i + 3] = __float2bfloat16(v.w);
}

// ---------------------------------------------------------------- fused QKV GEMM
// ROUND-2-PROVEN version: 128x128 tile, BK=32, linear LDS.
__global__ __launch_bounds__(256) void gemm_qkv(const __hip_bfloat16* __restrict__ A,
                                                const __hip_bfloat16* __restrict__ wq,
                                                const __hip_bfloat16* __restrict__ wk,
                                                const __hip_bfloat16* __restrict__ wv,
                                                const float* __restrict__ bq,
                                                const float* __restrict__ bk,
                                                const float* __restrict__ bv,
                                                __hip_bfloat16* __restrict__ qo,
                                                __hip_bfloat16* __restrict__ ko,
                                                __hip_bfloat16* __restrict__ vto) {
    __shared__ __hip_bfloat16 Al[128 * 32];
    __shared__ __hip_bfloat16 Bl[128 * 32];
    const int sel = blockIdx.x >> 3;
    const __hip_bfloat16* Bw = sel == 0 ? wq : sel == 1 ? wk : wv;
    const float* bias = sel == 0 ? bq : sel == 1 ? bk : bv;
    const int t = threadIdx.x, w = t >> 6, l = t & 63;
    const int wr = w >> 1, wc = w & 1, lr = l & 15, lg = l >> 4;
    const int m0 = blockIdx.y * 128, n0 = (blockIdx.x & 7) * 128;
    const int K = C_;

    f32x4 acc[4][4] = {};

    for (int k0 = 0; k0 < K; k0 += 32) {
#pragma unroll
        for (int it = 0; it < 2; ++it) {
            int i = t + it * 256;
            int r = i >> 2, c8 = (i & 3) * 8;
            gld_lds16(A + (size_t)(m0 + r) * K + k0 + c8, &Al[i * 8]);
            gld_lds16(Bw + (size_t)(n0 + r) * K + k0 + c8, &Bl[i * 8]);
        }
        __syncthreads();
        bf16x8 af[4], bfr[4];
#pragma unroll
        for (int mi = 0; mi < 4; ++mi)
            af[mi] = *(const bf16x8*)&Al[(wr * 64 + mi * 16 + lr) * 32 + lg * 8];
#pragma unroll
        for (int ni = 0; ni < 4; ++ni)
            bfr[ni] = *(const bf16x8*)&Bl[(wc * 64 + ni * 16 + lr) * 32 + lg * 8];
#pragma unroll
        for (int mi = 0; mi < 4; ++mi)
#pragma unroll
            for (int ni = 0; ni < 4; ++ni)
                acc[mi][ni] = __builtin_amdgcn_mfma_f32_16x16x32_bf16(
                    af[mi], bfr[ni], acc[mi][ni], 0, 0, 0);
        __syncthreads();
    }

#pragma unroll
    for (int mi = 0; mi < 4; ++mi) {
#pragma unroll
        for (int ni = 0; ni < 4; ++ni) {
            int col = n0 + wc * 64 + ni * 16 + lr;
            float bb = bias[col];
#pragma unroll
            for (int j = 0; j < 4; ++j) {
                int row = m0 + wr * 64 + mi * 16 + lg * 4 + j;
                float v = acc[mi][ni][j] + bb;
                int bb_ = row >> 10, nn = row & 1023;
                int hh = col >> 6, dd = col & 63;
                if (sel == 0) {
                    qo[(((size_t)bb_ * H_ + hh) * N_ + nn) * D_ + dd] =
                        __float2bfloat16(v * 0.125f);
                } else if (sel == 1) {
                    ko[(((size_t)bb_ * H_ + hh) * N_ + nn) * D_ + dd] =
                        __float2bfloat16(v);
                } else {
                    vto[(((size_t)bb_ * H_ + hh) * D_ + dd) * N_ + nn] =
                        __float2bfloat16(v);
                }
            }
        }
    }
}

// ---------------------------------------------------------------- output proj GEMM
__global__ __launch_bounds__(256) void gemm_out(const __hip_bfloat16* __restrict__ A,
                                                const __hip_bfloat16* __restrict__ Bw,
                                                const float* __restrict__ bias,
                                                float* __restrict__ out) {
    __shared__ __hip_bfloat16 Al[128 * 32];
    __shared__ __hip_bfloat16 Bl[128 * 32];
    const int t = threadIdx.x, w = t >> 6, l = t & 63;
    const int wr = w >> 1, wc = w & 1, lr = l & 15, lg = l >> 4;
    const int m0 = blockIdx.y * 128, n0 = blockIdx.x * 128;
    const int K = C_;

    f32x4 acc[4][4] = {};

    for (int k0 = 0; k0 < K; k0 += 32) {
#pragma unroll
        for (int it = 0; it < 2; ++it) {
            int i = t + it * 256;
            int r = i >> 2, c8 = (i & 3) * 8;
            gld_lds16(A + (size_t)(m0 + r) * K + k0 + c8, &Al[i * 8]);
            gld_lds16(Bw + (size_t)(n0 + r) * K + k0 + c8, &Bl[i * 8]);
        }
        __syncthreads();
        bf16x8 af[4], bfr[4];
#pragma unroll
        for (int mi = 0; mi < 4; ++mi)
            af[mi] = *(const bf16x8*)&Al[(wr * 64 + mi * 16 + lr) * 32 + lg * 8];
#pragma unroll
        for (int ni = 0; ni < 4; ++ni)
            bfr[ni] = *(const bf16x8*)&Bl[(wc * 64 + ni * 16 + lr) * 32 + lg * 8];
#pragma unroll
        for (int mi = 0; mi < 4; ++mi)
#pragma unroll
            for (int ni = 0; ni < 4; ++ni)
                acc[mi][ni] = __builtin_amdgcn_mfma_f32_16x16x32_bf16(
                    af[mi], bfr[ni], acc[mi][ni], 0, 0, 0);
        __syncthreads();
    }

#pragma unroll
    for (int mi = 0; mi < 4; ++mi)
#pragma unroll
        for (int ni = 0; ni < 4; ++ni) {
            int col = n0 + wc * 64 + ni * 16 + lr;
            float bb = bias[col];
#pragma unroll
            for (int j = 0; j < 4; ++j) {
                int row = m0 + wr * 64 + mi * 16 + lg * 4 + j;
                out[(size_t)row * C_ + col] = acc[mi][ni][j] + bb;
            }
        }
}

// ---------------------------------------------------------------- attention
// QBLK=128, 8 waves, grid 512. TRIPLE-buffered K/V + ONE s_barrier per K-tile
// (16 barriers vs round-14's 32). Race-freedom: a wave staging buf[(kt+2)%3]
// at iter kt+2 must be past B_{kt+1}, which requires all waves to have
// finished iter kt's compute (compute(kt) < s1(kt+1) < B_{kt+1} in program
// order) -> no WAR; each wave's vmcnt(6) before B_kt drains its KV(kt)
// stores -> B_kt publishes the tile. Bias in registers 2-deep (round-11
// scheme, vmcnt invariant identical); P relayout via cvt_pk+shfl (r10/r14).
// LDS = 3x8K (K) + 3x8K (V) + 4K (Pen) = 52 KB.
#define ATTN_ITER(KT, CB, SB, BCUR)                                                \
    {                                                                              \
        const int ktn_ = (KT) < 15 ? (KT) + 1 : 15;                                \
        const int ktb_ = (KT) < 14 ? (KT) + 2 : 15;                                \
        gld_lds16(kg0 + (size_t)ktn_ * 4096, &Kl[SB][(w * 64) * 8]);               \
        gld_lds16(vg0 + ktn_ * 64, &Vl[SB][(w * 64) * 8]);                         \
        __builtin_amdgcn_sched_barrier(0);                                         \
        asm volatile("s_waitcnt vmcnt(6)" ::: "memory");                           \
        __builtin_amdgcn_sched_barrier(0);                                         \
        __builtin_amdgcn_s_barrier();                                              \
        __builtin_amdgcn_sched_barrier(0);                                         \
        const __hip_bfloat16* Kb = &Kl[CB][0];                                     \
        float s[4][4];                                                             \
        __builtin_amdgcn_s_setprio(1);                                             \
        _Pragma("unroll")                                                          \
        for (int nkb = 0; nkb < 4; ++nkb) {                                        \
            f32x4 a = {};                                                          \
            _Pragma("unroll")                                                      \
            for (int half = 0; half < 2; ++half) {                                 \
                bf16x8 kf = *(const bf16x8*)                                       \
                    &Kb[(nkb * 16 + lr) * 64 + ((half * 32 + lg * 8) ^ swz)];      \
                a = __builtin_amdgcn_mfma_f32_16x16x32_bf16(kf, qf[half], a,       \
                                                            0, 0, 0);              \
            }                                                                      \
            f32x4 pen = *(const f32x4*)&Pen[(KT) * 64 + nkb * 16 + lg * 4];        \
            _Pragma("unroll")                                                      \
            for (int j = 0; j < 4; ++j) s[nkb][j] = a[j] + BCUR[nkb][j] + pen[j];  \
        }                                                                          \
        __builtin_amdgcn_s_setprio(0);                                             \
        __builtin_amdgcn_sched_barrier(0);                                         \
        _Pragma("unroll")                                                          \
        for (int nkb = 0; nkb < 4; ++nkb)                                          \
            BCUR[nkb] = *(const f32x4*)&brow[ktb_ * 64 + nkb * 16 + lg * 4];       \
        __builtin_amdgcn_sched_barrier(0);                                         \
        float tm = s[0][0];                                                        \
        _Pragma("unroll")                                                          \
        for (int nkb = 0; nkb < 4; ++nkb)                                          \
            _Pragma("unroll")                                                      \
            for (int j = 0; j < 4; ++j) tm = fmaxf(tm, s[nkb][j]);                 \
        tm = fmaxf(tm, __shfl_xor(tm, 16));                                        \
        tm = fmaxf(tm, __shfl_xor(tm, 32));                                        \
        const float mn = fmaxf(m_, tm);                                            \
        const float al = __expf(m_ - mn);                                          \
        m_ = mn;                                                                   \
        float ts = 0.f;                                                            \
        _Pragma("unroll")                                                          \
        for (int nkb = 0; nkb < 4; ++nkb)                                          \
            _Pragma("unroll")                                                      \
            for (int j = 0; j < 4; ++j) {                                          \
                float p = __expf(s[nkb][j] - mn);                                  \
                s[nkb][j] = p;                                                     \
                ts += p;                                                           \
            }                                                                      \
        ts += __shfl_xor(ts, 16);                                                  \
        ts += __shfl_xor(ts, 32);                                                  \
        l_ = l_ * al + ts;                                                         \
        unsigned pk0[4], pk1[4];                                                   \
        _Pragma("unroll")                                                          \
        for (int nkb = 0; nkb < 4; ++nkb) {                                        \
            pk0[nkb] = cvt_pk_bf16(s[nkb][0], s[nkb][1]);                          \
            pk1[nkb] = cvt_pk_bf16(s[nkb][2], s[nkb][3]);                          \
        }                                                                          \
        float alr[4];                                                              \
        _Pragma("unroll")                                                          \
        for (int j = 0; j < 4; ++j) alr[j] = __shfl(al, lg * 4 + j);               \
        _Pragma("unroll")                                                          \
        for (int db = 0; db < 4; ++db)                                             \
            _Pragma("unroll")                                                      \
            for (int j = 0; j < 4; ++j) acc[db][j] *= alr[j];                      \
        const __hip_bfloat16* Vb = &Vl[CB][0];                                     \
        __builtin_amdgcn_s_setprio(1);                                             \
        _Pragma("unroll")                                                          \
        for (int mh = 0; mh < 2; ++mh) {                                           \
            const int n0_ = 2 * mh, n1_ = 2 * mh + 1;                              \
            int e0a = __shfl((int)pk0[n0_], shi0), e0b = __shfl((int)pk0[n1_], shi0); \
            int e1a = __shfl((int)pk1[n0_], shi0), e1b = __shfl((int)pk1[n1_], shi0); \
            int e2a = __shfl((int)pk0[n0_], shi1), e2b = __shfl((int)pk0[n1_], shi1); \
            int e3a = __shfl((int)pk1[n0_], shi1), e3b = __shfl((int)pk1[n1_], shi1); \
            i32x4 pw;                                                              \
            pw[0] = lghi ? e0b : e0a;                                              \
            pw[1] = lghi ? e1b : e1a;                                              \
            pw[2] = lghi ? e2b : e2a;                                              \
            pw[3] = lghi ? e3b : e3a;                                              \
            bf16x8 paf = *(bf16x8*)&pw;                                            \
            _Pragma("unroll")                                                      \
            for (int db = 0; db < 4; ++db) {                                       \
                bf16x8 vf = *(const bf16x8*)                                       \
                    &Vb[(db * 16 + lr) * 64 + ((mh * 32 + lg * 8) ^ swz)];         \
                acc[db] = __builtin_amdgcn_mfma_f32_16x16x32_bf16(paf, vf,         \
                                                                  acc[db], 0, 0,  \
                                                                  0);              \
            }                                                                      \
        }                                                                          \
        __builtin_amdgcn_s_setprio(0);                                             \
        __builtin_amdgcn_sched_barrier(0);                                         \
    }

__global__ __launch_bounds__(512, 4) void attn_kernel(const __hip_bfloat16* __restrict__ q,
                                                      const __hip_bfloat16* __restrict__ k,
                                                      const __hip_bfloat16* __restrict__ vt,
                                                      const float* __restrict__ bias,
                                                      const int* __restrict__ mask,
                                                      __hip_bfloat16* __restrict__ ao) {
    const int orig = blockIdx.x;
    const int wg = (orig & 7) * 64 + (orig >> 3);  // bijective XCD swizzle (512 % 8 == 0)
    const int qt = wg & 7, h = (wg >> 3) & 15, b = wg >> 7;
    const int t = threadIdx.x, w = t >> 6, l = t & 63;
    const int lr = l & 15, lg = l >> 4;

    __shared__ __hip_bfloat16 Kl[3][64 * 64];  // 24 KB triple-buffered
    __shared__ __hip_bfloat16 Vl[3][64 * 64];  // 24 KB triple-buffered
    __shared__ float Pen[1024];                // mask penalties, 4 KB
    // total 52 KB

    const size_t bh = (size_t)b * H_ + h;
    const int qr0 = qt * 128;
    const int myrow = qr0 + w * 16 + lr;
    const int orow_base = qr0 + w * 16 + lg * 4;

    // ---- mask -> additive penalties in LDS (one-time)
    {
        int2 mi = *(const int2*)&mask[b * N_ + t * 2];
        float2 p;
        p.x = mi.x ? 0.f : -1e30f;
        p.y = mi.y ? 0.f : -1e30f;
        *(float2*)&Pen[t * 2] = p;
    }
    __syncthreads();

    // ---- K/V staging addresses (round-14 pattern: pre-swizzled src, linear dest)
    const int r0 = t >> 3;
    const int e0 = ((t & 7) * 8) ^ ((r0 & 7) << 3);
    const __hip_bfloat16* kg0 = k + (bh * N_ + r0) * D_ + e0;
    const __hip_bfloat16* vg0 = vt + (bh * D_ + r0) * N_ + e0;

    // ---- Q fragment (B-operand of swapped QK^T)
    bf16x8 qf[2];
#pragma unroll
    for (int half = 0; half < 2; ++half)
        qf[half] = *(const bf16x8*)&q[(bh * N_ + myrow) * D_ + half * 32 + lg * 8];

    const float* brow = bias + ((size_t)bh * N_ + myrow) * N_;
    const int swz = (lr & 7) << 3;
    const int shi0 = ((lg & 1) << 5) + lr;  // P-shfl sources (r10/r14-verified)
    const int shi1 = shi0 + 16;
    const bool lghi = (lg >> 1) != 0;

    f32x4 acc[4] = {};
    float m_ = -3e38f, l_ = 0.f;

    // ---- prologue: stage KV(0)->buf0 (2 ops); bias(0)->bA, bias(1)->bB (8 ops)
    __builtin_amdgcn_sched_barrier(0);
    gld_lds16(kg0, &Kl[0][(w * 64) * 8]);
    gld_lds16(vg0, &Vl[0][(w * 64) * 8]);
    f32x4 bA[4], bB[4];
#pragma unroll
    for (int nkb = 0; nkb < 4; ++nkb) {
        bA[nkb] = *(const f32x4*)&brow[nkb * 16 + lg * 4];
        bB[nkb] = *(const f32x4*)&brow[64 + nkb * 16 + lg * 4];
    }
    __builtin_amdgcn_sched_barrier(0);

    // buffers cycle %3, bias sets alternate %2 -> unroll in groups of 6 + tail 4
    for (int kt = 0; kt < 12; kt += 6) {
        ATTN_ITER(kt + 0, 0, 1, bA);
        ATTN_ITER(kt + 1, 1, 2, bB);
        ATTN_ITER(kt + 2, 2, 0, bA);
        ATTN_ITER(kt + 3, 0, 1, bB);
        ATTN_ITER(kt + 4, 1, 2, bA);
        ATTN_ITER(kt + 5, 2, 0, bB);
    }
    ATTN_ITER(12, 0, 1, bA);
    ATTN_ITER(13, 1, 2, bB);
    ATTN_ITER(14, 2, 0, bA);
    ATTN_ITER(15, 0, 1, bB);

    // keep clamped tail prefetch alive (anti-DCE, keeps vmcnt counts exact)
    float dummy = bA[0][0] + bA[1][0] + bA[2][0] + bA[3][0] +
                  bB[0][0] + bB[1][0] + bB[2][0] + bB[3][0];
    asm volatile("" :: "v"(dummy));

    // epilogue
    float linv[4];
#pragma unroll
    for (int j = 0; j < 4; ++j) linv[j] = 1.f / __shfl(l_, lg * 4 + j);
#pragma unroll
    for (int db = 0; db < 4; ++db)
#pragma unroll
        for (int j = 0; j < 4; ++j)
            ao[((size_t)b * N_ + orow_base + j) * C_ + h * 64 + db * 16 + lr] =
                __float2bfloat16(acc[db][j] * linv[j]);
}

// ---------------------------------------------------------------- launcher
extern "C" void kernel_launch(void* const* d_in, const int* in_sizes, int n_in,
                              void* d_out, int out_size, void* d_ws, size_t ws_size,
                              hipStream_t stream) {
    const float* x    = (const float*)d_in[0];
    const float* bias = (const float*)d_in[1];
    const int*   mask = (const int*)d_in[2];
    const float* Wq   = (const float*)d_in[3];
    const float* bq   = (const float*)d_in[4];
    const float* Wk   = (const float*)d_in[5];
    const float* bk   = (const float*)d_in[6];
    const float* Wv   = (const float*)d_in[7];
    const float* bv   = (const float*)d_in[8];
    const float* Wo   = (const float*)d_in[9];
    const float* bo   = (const float*)d_in[10];
    float* out = (float*)d_out;

    char* ws = (char*)d_ws;
    const size_t MB = 1u << 20;
    __hip_bfloat16* xb  = (__hip_bfloat16*)(ws + 0 * MB);   // 8 MB
    __hip_bfloat16* wqb = (__hip_bfloat16*)(ws + 8 * MB);   // 2 MB each
    __hip_bfloat16* wkb = (__hip_bfloat16*)(ws + 10 * MB);
    __hip_bfloat16* wvb = (__hip_bfloat16*)(ws + 12 * MB);
    __hip_bfloat16* wob = (__hip_bfloat16*)(ws + 14 * MB);
    __hip_bfloat16* qb  = (__hip_bfloat16*)(ws + 16 * MB);  // 8 MB
    __hip_bfloat16* kb  = (__hip_bfloat16*)(ws + 24 * MB);  // 8 MB
    __hip_bfloat16* vtb = (__hip_bfloat16*)(ws + 32 * MB);  // 8 MB
    __hip_bfloat16* aob = (__hip_bfloat16*)(ws + 40 * MB);  // 8 MB

    f2b_kernel<<<4096, 256, 0, stream>>>(x, xb, B_ * N_ * C_);
    f2b4_kernel<<<dim3(1024, 4), 256, 0, stream>>>(Wq, Wk, Wv, Wo, wqb, wkb, wvb, wob);

    gemm_qkv<<<dim3(24, 32), 256, 0, stream>>>(xb, wqb, wkb, wvb, bq, bk, bv, qb, kb, vtb);

    attn_kernel<<<512, 512, 0, stream>>>(qb, kb, vtb, bias, mask, aob);

    gemm_out<<<dim3(8, 32), 256, 0, stream>>>(aob, wob, bo, out);
}

// Round 17
// 143.292 us; speedup vs baseline: 1.1537x; 1.1537x over previous
//
#include <hip/hip_runtime.h>
#include <hip/hip_bf16.h>

#define B_ 4
#define N_ 1024
#define C_ 1024
#define H_ 16
#define D_ 64

typedef __attribute__((ext_vector_type(8))) short bf16x8;
typedef __attribute__((ext_vector_type(4))) float f32x4;
typedef __attribute__((ext_vector_type(4))) int i32x4;

__device__ __forceinline__ void gld_lds16(const void* g, void* l) {
    __builtin_amdgcn_global_load_lds(
        (const __attribute__((address_space(1))) void*)g,
        (__attribute__((address_space(3))) void*)l, 16, 0, 0);
}

__device__ __forceinline__ unsigned cvt_pk_bf16(float lo, float hi) {
    unsigned r;
    asm("v_cvt_pk_bf16_f32 %0, %1, %2" : "=v"(r) : "v"(lo), "v"(hi));
    return r;
}

// ---------------------------------------------------------------- fp32 -> bf16
__global__ __launch_bounds__(256) void f2b_kernel(const float* __restrict__ s,
                                                  __hip_bfloat16* __restrict__ d,
                                                  int n) {
    int i = (blockIdx.x * 256 + threadIdx.x) * 4;
    if (i < n) {
        float4 v = *(const float4*)&s[i];
        d[i + 0] = __float2bfloat16(v.x);
        d[i + 1] = __float2bfloat16(v.y);
        d[i + 2] = __float2bfloat16(v.z);
        d[i + 3] = __float2bfloat16(v.w);
    }
}

// 4 weight matrices in one dispatch (blockIdx.y selects)
__global__ __launch_bounds__(256) void f2b4_kernel(const float* __restrict__ w0,
                                                   const float* __restrict__ w1,
                                                   const float* __restrict__ w2,
                                                   const float* __restrict__ w3,
                                                   __hip_bfloat16* __restrict__ d0,
                                                   __hip_bfloat16* __restrict__ d1,
                                                   __hip_bfloat16* __restrict__ d2,
                                                   __hip_bfloat16* __restrict__ d3) {
    int sel = blockIdx.y;
    const float* s = sel == 0 ? w0 : sel == 1 ? w1 : sel == 2 ? w2 : w3;
    __hip_bfloat16* d = sel == 0 ? d0 : sel == 1 ? d1 : sel == 2 ? d2 : d3;
    int i = (blockIdx.x * 256 + threadIdx.x) * 4;
    float4 v = *(const float4*)&s[i];
    d[i + 0] = __float2bfloat16(v.x);
    d[i + 1] = __float2bfloat16(v.y);
    d[i + 2] = __float2bfloat16(v.z);
    d[i + 3] = __float2bfloat16(v.w);
}

// ---------------------------------------------------------------- fused QKV GEMM
// ROUND-2-PROVEN version: 128x128 tile, BK=32, linear LDS.
__global__ __launch_bounds__(256) void gemm_qkv(const __hip_bfloat16* __restrict__ A,
                                                const __hip_bfloat16* __restrict__ wq,
                                                const __hip_bfloat16* __restrict__ wk,
                                                const __hip_bfloat16* __restrict__ wv,
                                                const float* __restrict__ bq,
                                                const float* __restrict__ bk,
                                                const float* __restrict__ bv,
                                                __hip_bfloat16* __restrict__ qo,
                                                __hip_bfloat16* __restrict__ ko,
                                                __hip_bfloat16* __restrict__ vto) {
    __shared__ __hip_bfloat16 Al[128 * 32];
    __shared__ __hip_bfloat16 Bl[128 * 32];
    const int sel = blockIdx.x >> 3;
    const __hip_bfloat16* Bw = sel == 0 ? wq : sel == 1 ? wk : wv;
    const float* bias = sel == 0 ? bq : sel == 1 ? bk : bv;
    const int t = threadIdx.x, w = t >> 6, l = t & 63;
    const int wr = w >> 1, wc = w & 1, lr = l & 15, lg = l >> 4;
    const int m0 = blockIdx.y * 128, n0 = (blockIdx.x & 7) * 128;
    const int K = C_;

    f32x4 acc[4][4] = {};

    for (int k0 = 0; k0 < K; k0 += 32) {
#pragma unroll
        for (int it = 0; it < 2; ++it) {
            int i = t + it * 256;
            int r = i >> 2, c8 = (i & 3) * 8;
            gld_lds16(A + (size_t)(m0 + r) * K + k0 + c8, &Al[i * 8]);
            gld_lds16(Bw + (size_t)(n0 + r) * K + k0 + c8, &Bl[i * 8]);
        }
        __syncthreads();
        bf16x8 af[4], bfr[4];
#pragma unroll
        for (int mi = 0; mi < 4; ++mi)
            af[mi] = *(const bf16x8*)&Al[(wr * 64 + mi * 16 + lr) * 32 + lg * 8];
#pragma unroll
        for (int ni = 0; ni < 4; ++ni)
            bfr[ni] = *(const bf16x8*)&Bl[(wc * 64 + ni * 16 + lr) * 32 + lg * 8];
#pragma unroll
        for (int mi = 0; mi < 4; ++mi)
#pragma unroll
            for (int ni = 0; ni < 4; ++ni)
                acc[mi][ni] = __builtin_amdgcn_mfma_f32_16x16x32_bf16(
                    af[mi], bfr[ni], acc[mi][ni], 0, 0, 0);
        __syncthreads();
    }

#pragma unroll
    for (int mi = 0; mi < 4; ++mi) {
#pragma unroll
        for (int ni = 0; ni < 4; ++ni) {
            int col = n0 + wc * 64 + ni * 16 + lr;
            float bb = bias[col];
#pragma unroll
            for (int j = 0; j < 4; ++j) {
                int row = m0 + wr * 64 + mi * 16 + lg * 4 + j;
                float v = acc[mi][ni][j] + bb;
                int bb_ = row >> 10, nn = row & 1023;
                int hh = col >> 6, dd = col & 63;
                if (sel == 0) {
                    qo[(((size_t)bb_ * H_ + hh) * N_ + nn) * D_ + dd] =
                        __float2bfloat16(v * 0.125f);
                } else if (sel == 1) {
                    ko[(((size_t)bb_ * H_ + hh) * N_ + nn) * D_ + dd] =
                        __float2bfloat16(v);
                } else {
                    vto[(((size_t)bb_ * H_ + hh) * D_ + dd) * N_ + nn] =
                        __float2bfloat16(v);
                }
            }
        }
    }
}

// ---------------------------------------------------------------- output proj GEMM
__global__ __launch_bounds__(256) void gemm_out(const __hip_bfloat16* __restrict__ A,
                                                const __hip_bfloat16* __restrict__ Bw,
                                                const float* __restrict__ bias,
                                                float* __restrict__ out) {
    __shared__ __hip_bfloat16 Al[128 * 32];
    __shared__ __hip_bfloat16 Bl[128 * 32];
    const int t = threadIdx.x, w = t >> 6, l = t & 63;
    const int wr = w >> 1, wc = w & 1, lr = l & 15, lg = l >> 4;
    const int m0 = blockIdx.y * 128, n0 = blockIdx.x * 128;
    const int K = C_;

    f32x4 acc[4][4] = {};

    for (int k0 = 0; k0 < K; k0 += 32) {
#pragma unroll
        for (int it = 0; it < 2; ++it) {
            int i = t + it * 256;
            int r = i >> 2, c8 = (i & 3) * 8;
            gld_lds16(A + (size_t)(m0 + r) * K + k0 + c8, &Al[i * 8]);
            gld_lds16(Bw + (size_t)(n0 + r) * K + k0 + c8, &Bl[i * 8]);
        }
        __syncthreads();
        bf16x8 af[4], bfr[4];
#pragma unroll
        for (int mi = 0; mi < 4; ++mi)
            af[mi] = *(const bf16x8*)&Al[(wr * 64 + mi * 16 + lr) * 32 + lg * 8];
#pragma unroll
        for (int ni = 0; ni < 4; ++ni)
            bfr[ni] = *(const bf16x8*)&Bl[(wc * 64 + ni * 16 + lr) * 32 + lg * 8];
#pragma unroll
        for (int mi = 0; mi < 4; ++mi)
#pragma unroll
            for (int ni = 0; ni < 4; ++ni)
                acc[mi][ni] = __builtin_amdgcn_mfma_f32_16x16x32_bf16(
                    af[mi], bfr[ni], acc[mi][ni], 0, 0, 0);
        __syncthreads();
    }

#pragma unroll
    for (int mi = 0; mi < 4; ++mi)
#pragma unroll
        for (int ni = 0; ni < 4; ++ni) {
            int col = n0 + wc * 64 + ni * 16 + lr;
            float bb = bias[col];
#pragma unroll
            for (int j = 0; j < 4; ++j) {
                int row = m0 + wr * 64 + mi * 16 + lg * 4 + j;
                out[(size_t)row * C_ + col] = acc[mi][ni][j] + bb;
            }
        }
}

// ---------------------------------------------------------------- attention
// ROUND-14 base (best, 153.98us) + per-block TILE-PHASE STAGGER: block
// processes K-tiles in order p(kt) = (kt + phase) & 15, phase = orig & 15.
// Rationale: without stagger all blocks sweep the same bias column-window
// (addr = kt*256 mod 4096) in lockstep -> HBM channel-subset convoy.
// Online softmax is tile-order-invariant, so only K/V/bias/Pen tile indices
// change; schedule, vmcnt counts and swizzles are byte-identical to r14.
#define ATTN_ITER(KT, CB, SB)                                                      \
    {                                                                              \
        const int ktn_ = (KT) < 15 ? (KT) + 1 : 15;                                \
        const int pn_ = (ktn_ + phase) & 15;  /* staged tile (physical) */         \
        const int pk_ = ((KT) + phase) & 15;  /* computed tile (physical) */       \
        gld_lds16(kg0 + (size_t)pn_ * 4096, &Kl[SB][(w * 64) * 8]);                \
        gld_lds16(vg0 + pn_ * 64, &Vl[SB][(w * 64) * 8]);                          \
        __builtin_amdgcn_sched_barrier(0);                                         \
        asm volatile("s_waitcnt vmcnt(6)" ::: "memory");                           \
        __builtin_amdgcn_sched_barrier(0);                                         \
        __builtin_amdgcn_s_barrier();                                              \
        __builtin_amdgcn_sched_barrier(0);                                         \
        const __hip_bfloat16* Kb = &Kl[CB][0];                                     \
        f32x4 a_[4];                                                               \
        __builtin_amdgcn_s_setprio(1);                                             \
        _Pragma("unroll")                                                          \
        for (int nkb = 0; nkb < 4; ++nkb) {                                        \
            f32x4 a = {};                                                          \
            _Pragma("unroll")                                                      \
            for (int half = 0; half < 2; ++half) {                                 \
                bf16x8 kf = *(const bf16x8*)                                       \
                    &Kb[(nkb * 16 + lr) * 64 + ((half * 32 + lg * 8) ^ swz)];      \
                a = __builtin_amdgcn_mfma_f32_16x16x32_bf16(kf, qf[half], a,       \
                                                            0, 0, 0);              \
            }                                                                      \
            a_[nkb] = a;                                                           \
        }                                                                          \
        __builtin_amdgcn_s_setprio(0);                                             \
        __builtin_amdgcn_sched_barrier(0);                                         \
        asm volatile("s_waitcnt vmcnt(2)" ::: "memory");                           \
        __builtin_amdgcn_sched_barrier(0);                                         \
        float s[4][4];                                                             \
        _Pragma("unroll")                                                          \
        for (int nkb = 0; nkb < 4; ++nkb) {                                        \
            f32x4 bb = *(const f32x4*)&Bb[w][lr][((nkb * 4 + lg) ^ lr) * 4];       \
            f32x4 pen = *(const f32x4*)&Pen[pk_ * 64 + nkb * 16 + lg * 4];         \
            _Pragma("unroll")                                                      \
            for (int j = 0; j < 4; ++j) s[nkb][j] = a_[nkb][j] + bb[j] + pen[j];   \
        }                                                                          \
        __builtin_amdgcn_sched_barrier(0);                                         \
        asm volatile("s_waitcnt lgkmcnt(0)" ::: "memory");                         \
        __builtin_amdgcn_sched_barrier(0);                                         \
        _Pragma("unroll")                                                          \
        for (int i_ = 0; i_ < 4; ++i_)                                             \
            gld_lds16(bg[i_] + pn_ * 64, bl + i_ * 256);                           \
        __builtin_amdgcn_sched_barrier(0);                                         \
        float tm = s[0][0];                                                        \
        _Pragma("unroll")                                                          \
        for (int nkb = 0; nkb < 4; ++nkb)                                          \
            _Pragma("unroll")                                                      \
            for (int j = 0; j < 4; ++j) tm = fmaxf(tm, s[nkb][j]);                 \
        tm = fmaxf(tm, __shfl_xor(tm, 16));                                        \
        tm = fmaxf(tm, __shfl_xor(tm, 32));                                        \
        const float mn = fmaxf(m_, tm);                                            \
        const float al = __expf(m_ - mn);                                          \
        m_ = mn;                                                                   \
        float ts = 0.f;                                                            \
        _Pragma("unroll")                                                          \
        for (int nkb = 0; nkb < 4; ++nkb)                                          \
            _Pragma("unroll")                                                      \
            for (int j = 0; j < 4; ++j) {                                          \
                float p = __expf(s[nkb][j] - mn);                                  \
                s[nkb][j] = p;                                                     \
                ts += p;                                                           \
            }                                                                      \
        ts += __shfl_xor(ts, 16);                                                  \
        ts += __shfl_xor(ts, 32);                                                  \
        l_ = l_ * al + ts;                                                         \
        unsigned pk0[4], pk1[4];                                                   \
        _Pragma("unroll")                                                          \
        for (int nkb = 0; nkb < 4; ++nkb) {                                        \
            pk0[nkb] = cvt_pk_bf16(s[nkb][0], s[nkb][1]);                          \
            pk1[nkb] = cvt_pk_bf16(s[nkb][2], s[nkb][3]);                          \
        }                                                                          \
        float alr[4];                                                              \
        _Pragma("unroll")                                                          \
        for (int j = 0; j < 4; ++j) alr[j] = __shfl(al, lg * 4 + j);               \
        _Pragma("unroll")                                                          \
        for (int db = 0; db < 4; ++db)                                             \
            _Pragma("unroll")                                                      \
            for (int j = 0; j < 4; ++j) acc[db][j] *= alr[j];                      \
        const __hip_bfloat16* Vb = &Vl[CB][0];                                     \
        __builtin_amdgcn_s_setprio(1);                                             \
        _Pragma("unroll")                                                          \
        for (int mh = 0; mh < 2; ++mh) {                                           \
            const int n0_ = 2 * mh, n1_ = 2 * mh + 1;                              \
            int e0a = __shfl((int)pk0[n0_], shi0), e0b = __shfl((int)pk0[n1_], shi0); \
            int e1a = __shfl((int)pk1[n0_], shi0), e1b = __shfl((int)pk1[n1_], shi0); \
            int e2a = __shfl((int)pk0[n0_], shi1), e2b = __shfl((int)pk0[n1_], shi1); \
            int e3a = __shfl((int)pk1[n0_], shi1), e3b = __shfl((int)pk1[n1_], shi1); \
            i32x4 pw;                                                              \
            pw[0] = lghi ? e0b : e0a;                                              \
            pw[1] = lghi ? e1b : e1a;                                              \
            pw[2] = lghi ? e2b : e2a;                                              \
            pw[3] = lghi ? e3b : e3a;                                              \
            bf16x8 paf = *(bf16x8*)&pw;                                            \
            _Pragma("unroll")                                                      \
            for (int db = 0; db < 4; ++db) {                                       \
                bf16x8 vf = *(const bf16x8*)                                       \
                    &Vb[(db * 16 + lr) * 64 + ((mh * 32 + lg * 8) ^ swz)];         \
                acc[db] = __builtin_amdgcn_mfma_f32_16x16x32_bf16(paf, vf,         \
                                                                  acc[db], 0, 0,  \
                                                                  0);              \
            }                                                                      \
        }                                                                          \
        __builtin_amdgcn_s_setprio(0);                                             \
        __builtin_amdgcn_sched_barrier(0);                                         \
        __builtin_amdgcn_s_barrier();                                              \
        __builtin_amdgcn_sched_barrier(0);                                         \
    }

__global__ __launch_bounds__(512, 4) void attn_kernel(const __hip_bfloat16* __restrict__ q,
                                                      const __hip_bfloat16* __restrict__ k,
                                                      const __hip_bfloat16* __restrict__ vt,
                                                      const float* __restrict__ bias,
                                                      const int* __restrict__ mask,
                                                      __hip_bfloat16* __restrict__ ao) {
    const int orig = blockIdx.x;
    const int wg = (orig & 7) * 64 + (orig >> 3);  // bijective XCD swizzle (512 % 8 == 0)
    const int qt = wg & 7, h = (wg >> 3) & 15, b = wg >> 7;
    const int phase = orig & 15;                   // per-block tile-phase stagger
    const int t = threadIdx.x, w = t >> 6, l = t & 63;
    const int lr = l & 15, lg = l >> 4;

    __shared__ __hip_bfloat16 Kl[2][64 * 64];  // 16 KB double-buffered
    __shared__ __hip_bfloat16 Vl[2][64 * 64];  // 16 KB double-buffered
    __shared__ float Pen[1024];                // mask penalties, 4 KB
    __shared__ float Bb[8][16][64];            // per-wave bias tile, 32 KB
    // total 68 KB -> 2 blocks/CU

    const size_t bh = (size_t)b * H_ + h;
    const int qr0 = qt * 128;
    const int myrow = qr0 + w * 16 + lr;
    const int orow_base = qr0 + w * 16 + lg * 4;

    // ---- mask -> additive penalties in LDS (one-time)
    {
        int2 mi = *(const int2*)&mask[b * N_ + t * 2];
        float2 p;
        p.x = mi.x ? 0.f : -1e30f;
        p.y = mi.y ? 0.f : -1e30f;
        *(float2*)&Pen[t * 2] = p;
    }
    __syncthreads();

    // ---- K/V staging addresses (round-14 pattern)
    const int r0 = t >> 3;
    const int e0 = ((t & 7) * 8) ^ ((r0 & 7) << 3);
    const __hip_bfloat16* kg0 = k + (bh * N_ + r0) * D_ + e0;
    const __hip_bfloat16* vg0 = vt + (bh * D_ + r0) * N_ + e0;

    // ---- bias staging addresses: inst i covers rows i*4+rb (rb=l>>4),
    // stored chunk pb (=l&15) holds global chunk pb^row (chunk-XOR swizzle).
    const int rb = l >> 4, pb = l & 15;
    const float* bg[4];
#pragma unroll
    for (int i = 0; i < 4; ++i) {
        int ri = i * 4 + rb;
        bg[i] = bias + ((size_t)bh * N_ + qr0 + w * 16 + ri) * N_ + (pb ^ ri) * 4;
    }
    float* bl = &Bb[w][0][0];  // wave-uniform LDS base

    // ---- Q fragment (B-operand of swapped QK^T)
    bf16x8 qf[2];
#pragma unroll
    for (int half = 0; half < 2; ++half)
        qf[half] = *(const bf16x8*)&q[(bh * N_ + myrow) * D_ + half * 32 + lg * 8];

    const int swz = (lr & 7) << 3;
    const int shi0 = ((lg & 1) << 5) + lr;  // P-shfl sources (round-10/14-verified)
    const int shi1 = shi0 + 16;
    const bool lghi = (lg >> 1) != 0;

    f32x4 acc[4] = {};
    float m_ = -3e38f, l_ = 0.f;

    // ---- prologue: stage KV(p(0)) (2 ops) + bias(p(0)) (4 ops): 6 in flight
    __builtin_amdgcn_sched_barrier(0);
    gld_lds16(kg0 + (size_t)phase * 4096, &Kl[0][(w * 64) * 8]);
    gld_lds16(vg0 + phase * 64, &Vl[0][(w * 64) * 8]);
#pragma unroll
    for (int i = 0; i < 4; ++i) gld_lds16(bg[i] + phase * 64, bl + i * 256);
    __builtin_amdgcn_sched_barrier(0);

    for (int kt = 0; kt < 16; kt += 2) {
        ATTN_ITER(kt, 0, 1);
        ATTN_ITER(kt + 1, 1, 0);
    }

    // epilogue
    float linv[4];
#pragma unroll
    for (int j = 0; j < 4; ++j) linv[j] = 1.f / __shfl(l_, lg * 4 + j);
#pragma unroll
    for (int db = 0; db < 4; ++db)
#pragma unroll
        for (int j = 0; j < 4; ++j)
            ao[((size_t)b * N_ + orow_base + j) * C_ + h * 64 + db * 16 + lr] =
                __float2bfloat16(acc[db][j] * linv[j]);
}

// ---------------------------------------------------------------- launcher
extern "C" void kernel_launch(void* const* d_in, const int* in_sizes, int n_in,
                              void* d_out, int out_size, void* d_ws, size_t ws_size,
                              hipStream_t stream) {
    const float* x    = (const float*)d_in[0];
    const float* bias = (const float*)d_in[1];
    const int*   mask = (const int*)d_in[2];
    const float* Wq   = (const float*)d_in[3];
    const float* bq   = (const float*)d_in[4];
    const float* Wk   = (const float*)d_in[5];
    const float* bk   = (const float*)d_in[6];
    const float* Wv   = (const float*)d_in[7];
    const float* bv   = (const float*)d_in[8];
    const float* Wo   = (const float*)d_in[9];
    const float* bo   = (const float*)d_in[10];
    float* out = (float*)d_out;

    char* ws = (char*)d_ws;
    const size_t MB = 1u << 20;
    __hip_bfloat16* xb  = (__hip_bfloat16*)(ws + 0 * MB);   // 8 MB
    __hip_bfloat16* wqb = (__hip_bfloat16*)(ws + 8 * MB);   // 2 MB each
    __hip_bfloat16* wkb = (__hip_bfloat16*)(ws + 10 * MB);
    __hip_bfloat16* wvb = (__hip_bfloat16*)(ws + 12 * MB);
    __hip_bfloat16* wob = (__hip_bfloat16*)(ws + 14 * MB);
    __hip_bfloat16* qb  = (__hip_bfloat16*)(ws + 16 * MB);  // 8 MB
    __hip_bfloat16* kb  = (__hip_bfloat16*)(ws + 24 * MB);  // 8 MB
    __hip_bfloat16* vtb = (__hip_bfloat16*)(ws + 32 * MB);  // 8 MB
    __hip_bfloat16* aob = (__hip_bfloat16*)(ws + 40 * MB);  // 8 MB

    f2b_kernel<<<4096, 256, 0, stream>>>(x, xb, B_ * N_ * C_);
    f2b4_kernel<<<dim3(1024, 4), 256, 0, stream>>>(Wq, Wk, Wv, Wo, wqb, wkb, wvb, wob);

    gemm_qkv<<<dim3(24, 32), 256, 0, stream>>>(xb, wqb, wkb, wvb, bq, bk, bv, qb, kb, vtb);

    attn_kernel<<<512, 512, 0, stream>>>(qb, kb, vtb, bias, mask, aob);

    gemm_out<<<dim3(8, 32), 256, 0, stream>>>(aob, wob, bo, out);
}